// Round 4
// baseline (1028.938 us; speedup 1.0000x reference)
//
#include <hip/hip_runtime.h>
#include <math.h>

#define NN 50000
#define EE 800000
#define FIN 128
#define NH 5
#define HC 160
#define NG 64
#define CHUNK 384
#define NB 160
#define EPB 5000
#define NW 12500

__device__ __forceinline__ float lrelu(float x, float s) { return x >= 0.f ? x : s * x; }

__device__ __forceinline__ unsigned short f2bf(float x) {
    unsigned u = __float_as_uint(x);
    unsigned r = (u + 0x7fffu + ((u >> 16) & 1u)) >> 16;
    return (unsigned short)r;
}
__device__ __forceinline__ float bf2f(unsigned short b) {
    return __uint_as_float(((unsigned)b) << 16);
}

// ---------------- per-graph row ranges via binary search (batch sorted)
__global__ void prep_kernel(const int* __restrict__ batch, int* gstart, int* gcnt) {
    int i = threadIdx.x;
    if (i < NG) {
        int lo = 0, hi = NN;
        while (lo < hi) { int m = (lo + hi) >> 1; if (batch[m] < i) lo = m + 1; else hi = m; }
        int s = lo;
        lo = 0; hi = NN;
        int g1 = i + 1;
        while (lo < hi) { int m = (lo + hi) >> 1; if (batch[m] < g1) lo = m + 1; else hi = m; }
        gstart[i] = s;
        gcnt[i] = lo - s;
    }
}

// ---------------- per-block LDS histogram of dst (byte-packed, no global atomics)
__global__ __launch_bounds__(256) void hist_kernel(const int* __restrict__ ei,
                                                   unsigned* __restrict__ hist_g) {
    __shared__ unsigned lh[NW];
    int b = blockIdx.x, tid = threadIdx.x;
    for (int w = tid; w < NW; w += 256) lh[w] = 0;
    __syncthreads();
    const int* dstp = ei + EE + b * EPB;
    for (int i = tid; i < EPB; i += 256) {
        int d = dstp[i];
        atomicAdd(&lh[d >> 2], 1u << ((d & 3) * 8));
    }
    __syncthreads();
    unsigned* outp = hist_g + (size_t)b * NW;
    for (int w = tid; w < NW; w += 256) outp[w] = lh[w];
}

// ---------------- column scan over blocks: per-(block,bin) base + total deg
__global__ void sscan_kernel(const unsigned* __restrict__ hist_g,
                             unsigned short* __restrict__ base_g, int* __restrict__ deg) {
    int w = blockIdx.x * 256 + threadIdx.x;
    if (w >= NW) return;
    unsigned r0 = 0, r1 = 0, r2 = 0, r3 = 0;
    for (int b = 0; b < NB; b++) {
        unsigned x = hist_g[(size_t)b * NW + w];
        uint2 st;
        st.x = r0 | (r1 << 16);
        st.y = r2 | (r3 << 16);
        *reinterpret_cast<uint2*>(&base_g[(size_t)b * NN + 4 * w]) = st;
        r0 += x & 0xffu; r1 += (x >> 8) & 0xffu; r2 += (x >> 16) & 0xffu; r3 += (x >> 24) & 0xffu;
    }
    uint4 dv; dv.x = r0; dv.y = r1; dv.z = r2; dv.w = r3;
    *reinterpret_cast<uint4*>(&deg[4 * w]) = dv;
}

// ------------------------------------------------------- 3-phase parallel scan
__global__ void scan1_kernel(const int* __restrict__ deg, int* bsum) {
    __shared__ int ws[4];
    int tid = threadIdx.x, lane = tid & 63, wid = tid >> 6;
    int i = blockIdx.x * 256 + tid;
    int v = (i < NN) ? deg[i] : 0;
    for (int o = 32; o >= 1; o >>= 1) v += __shfl_down(v, o, 64);
    if (lane == 0) ws[wid] = v;
    __syncthreads();
    if (tid == 0) bsum[blockIdx.x] = ws[0] + ws[1] + ws[2] + ws[3];
}

__global__ void scan2_kernel(int* bsum, int* boff) {
    __shared__ int ws[4];
    int tid = threadIdx.x, lane = tid & 63, wid = tid >> 6;
    int v = (tid < 196) ? bsum[tid] : 0;
    int x = v;
    for (int o = 1; o < 64; o <<= 1) {
        int t = __shfl_up(x, o, 64);
        if (lane >= o) x += t;
    }
    if (lane == 63) ws[wid] = x;
    __syncthreads();
    if (tid == 0) {
        int acc = 0;
        for (int w = 0; w < 4; w++) { int t = ws[w]; ws[w] = acc; acc += t; }
    }
    __syncthreads();
    if (tid < 196) boff[tid] = x + ws[wid] - v;
}

__global__ void scan3_kernel(const int* __restrict__ deg, const int* __restrict__ boff,
                             int* off) {
    __shared__ int ws[4];
    int tid = threadIdx.x, lane = tid & 63, wid = tid >> 6;
    int i = blockIdx.x * 256 + tid;
    int v = (i < NN) ? deg[i] : 0;
    int x = v;
    for (int o = 1; o < 64; o <<= 1) {
        int t = __shfl_up(x, o, 64);
        if (lane >= o) x += t;
    }
    if (lane == 63) ws[wid] = x;
    __syncthreads();
    if (tid == 0) {
        int acc = 0;
        for (int w = 0; w < 4; w++) { int t = ws[w]; ws[w] = acc; acc += t; }
    }
    __syncthreads();
    int incl = x + ws[wid] + boff[blockIdx.x];
    if (i < NN) off[i + 1] = incl;
    if (i == 0) off[0] = 0;
}

// ---------------- rank via LDS + write packed edge record (no global atomics)
__global__ __launch_bounds__(256) void scatter_kernel(const int* __restrict__ ei,
                                                      const float* __restrict__ ea,
                                                      const unsigned short* __restrict__ base_g,
                                                      const int* __restrict__ soff,
                                                      uint4* __restrict__ erec) {
    __shared__ unsigned lc[NW];
    int b = blockIdx.x, tid = threadIdx.x;
    for (int w = tid; w < NW; w += 256) lc[w] = 0;
    __syncthreads();
    int e0 = b * EPB;
    const unsigned short* brow = base_g + (size_t)b * NN;
    for (int i = tid; i < EPB; i += 256) {
        int e = e0 + i;
        int d = ei[EE + e];
        int sh = (d & 3) * 8;
        unsigned old = atomicAdd(&lc[d >> 2], 1u << sh);
        int r = (int)((old >> sh) & 0xffu);
        int pos = soff[d] + (int)brow[d] + r;
        uint4 rec;
        rec.x = (unsigned)ei[e];
        rec.y = (unsigned)e;
        rec.z = __float_as_uint(ea[e]);
        rec.w = 0;
        erec[pos] = rec;
    }
}

// -------------------------------------- s[h] = dot(we[h*32: ], ae[h]) per layer
__global__ void preps_kernel(const float* we1, const float* ae1,
                             const float* we2, const float* ae2, float* s_out) {
    int tid = threadIdx.x;
    if (tid < 10) {
        const float* we = (tid < 5) ? we1 : we2;
        const float* ae = (tid < 5) ? ae1 : ae2;
        int h = tid % 5;
        float s = 0.f;
        for (int c = 0; c < 32; c++) s += we[h * 32 + c] * ae[h * 32 + c];
        s_out[tid] = s;
    }
}

#define ROWFMA(i, s) { acc[i].x += (s)*w4.x; acc[i].y += (s)*w4.y; acc[i].z += (s)*w4.z; acc[i].w += (s)*w4.w; }

// ---- h = A @ W, tile M=64, thread = 16 rows x 4 cols.
// BF: bf16 out + att-dot epilogue. !BF: fp32 out with bias+lrelu (merge MLP).
template <int K, bool BF>
__global__ __launch_bounds__(160) void gemm_kernel(const float* __restrict__ A,
                                                   const float* __restrict__ W,
                                                   const float* __restrict__ a_s,
                                                   const float* __restrict__ a_d,
                                                   const float* __restrict__ bias,
                                                   unsigned short* __restrict__ out_bf,
                                                   float* __restrict__ out_f,
                                                   float* al_s, float* al_d) {
    const int SUBSTRIDE = K * 16 + 4;
    __shared__ float smem[10256];
    int t = threadIdx.x;
    int sub = t / 40, cg = t - sub * 40;
    int base = blockIdx.x * 64;

    for (int idx = t; idx < 64 * K; idx += 160) {
        int r = idx / K, k = idx - r * K;
        int row = base + r;
        float v = (row < NN) ? A[(size_t)row * K + k] : 0.f;
        smem[(r >> 4) * SUBSTRIDE + k * 16 + (r & 15)] = v;
    }
    __syncthreads();

    float4 acc[16];
#pragma unroll
    for (int r = 0; r < 16; r++) acc[r] = make_float4(0.f, 0.f, 0.f, 0.f);

    const float* Wp = W + cg * 4;
    const float* xbase = &smem[sub * SUBSTRIDE];
    for (int k = 0; k < K; k++) {
        float4 w4 = *reinterpret_cast<const float4*>(Wp + (size_t)k * HC);
        const float4* xr = reinterpret_cast<const float4*>(xbase + k * 16);
        float4 q0 = xr[0], q1 = xr[1], q2 = xr[2], q3 = xr[3];
        ROWFMA(0, q0.x) ROWFMA(1, q0.y) ROWFMA(2, q0.z) ROWFMA(3, q0.w)
        ROWFMA(4, q1.x) ROWFMA(5, q1.y) ROWFMA(6, q1.z) ROWFMA(7, q1.w)
        ROWFMA(8, q2.x) ROWFMA(9, q2.y) ROWFMA(10, q2.z) ROWFMA(11, q2.w)
        ROWFMA(12, q3.x) ROWFMA(13, q3.y) ROWFMA(14, q3.z) ROWFMA(15, q3.w)
    }

    if (!BF) {
        float4 b4 = *reinterpret_cast<const float4*>(bias + cg * 4);
#pragma unroll
        for (int r = 0; r < 16; r++) {
            int row = base + sub * 16 + r;
            if (row < NN) {
                float4 o;
                o.x = lrelu(acc[r].x + b4.x, 0.01f);
                o.y = lrelu(acc[r].y + b4.y, 0.01f);
                o.z = lrelu(acc[r].z + b4.z, 0.01f);
                o.w = lrelu(acc[r].w + b4.w, 0.01f);
                *reinterpret_cast<float4*>(&out_f[(size_t)row * HC + cg * 4]) = o;
            }
        }
        return;
    }

#pragma unroll
    for (int r = 0; r < 16; r++) {
        int row = base + sub * 16 + r;
        if (row < NN) {
            uint2 p;
            p.x = (unsigned)f2bf(acc[r].x) | ((unsigned)f2bf(acc[r].y) << 16);
            p.y = (unsigned)f2bf(acc[r].z) | ((unsigned)f2bf(acc[r].w) << 16);
            *reinterpret_cast<uint2*>(&out_bf[(size_t)row * HC + cg * 4]) = p;
        }
    }

    __syncthreads();
    float* hs = smem;
#pragma unroll
    for (int r = 0; r < 16; r++) {
        *reinterpret_cast<float4*>(&hs[(sub * 16 + r) * HC + cg * 4]) = acc[r];
    }
    __syncthreads();
    for (int task = t; task < 640; task += 160) {
        int r = task / 10, rem = task - r * 10;
        int hd = rem >> 1, sd = rem & 1;
        int row = base + r;
        if (row < NN) {
            const float* av = sd ? a_d : a_s;
            float s = 0.f;
#pragma unroll
            for (int c = 0; c < 32; c++) s += hs[r * HC + hd * 32 + c] * av[hd * 32 + c];
            float* dst = sd ? al_d : al_s;
            dst[row * NH + hd] = s;
        }
    }
}

// ------------- per-node: segment softmax + weighted gather + bias/lrelu/LN
__global__ __launch_bounds__(192) void aggregate_kernel(
    const int* __restrict__ soff, const uint4* __restrict__ erec,
    const unsigned short* __restrict__ hfeat, const float* __restrict__ al_s,
    const float* __restrict__ al_d, const float* __restrict__ s_e,
    const float* __restrict__ bias, const float* __restrict__ g_ln,
    const float* __restrict__ b_ln,
    float* __restrict__ alpha_out, float* __restrict__ x_out) {
    int n = blockIdx.x;
    int tid = threadIdx.x;
    int lane = tid & 63, wid = tid >> 6;
    int s0 = soff[n];
    int deg = soff[n + 1] - s0;
    int items = deg + 1;

    __shared__ float w_sh[CHUNK * NH];
    __shared__ int isrc_sh[CHUNK];
    __shared__ int ieid_sh[CHUNK];
    __shared__ float sm[NH], sdinv[NH];
    __shared__ float sh_ad[NH], sh_se[NH];
    __shared__ float wred[18], wred2[15];
    __shared__ float stat[2];
    __shared__ float emean_sh;

    if (tid < NH) { sh_ad[tid] = al_d[n * NH + tid]; sh_se[tid] = s_e[tid]; }
    __syncthreads();
    float adr[NH], ser[NH];
#pragma unroll
    for (int h = 0; h < NH; h++) { adr[h] = sh_ad[h]; ser[h] = sh_se[h]; }

    float v = 0.f;

    if (items <= CHUNK) {
        float lm[NH];
#pragma unroll
        for (int h = 0; h < NH; h++) lm[h] = -3.0e38f;
        float eas = 0.f;
        for (int i = tid; i < deg; i += 192) {
            uint4 rec = erec[s0 + i];
            int src = (int)rec.x;
            float eav = __uint_as_float(rec.z);
            isrc_sh[i] = src;
            ieid_sh[i] = (int)rec.y;
            eas += eav;
#pragma unroll
            for (int h = 0; h < NH; h++) {
                float r = lrelu(al_s[src * NH + h] + adr[h] + eav * ser[h], 0.2f);
                w_sh[i * NH + h] = r;
                lm[h] = fmaxf(lm[h], r);
            }
        }
        for (int o = 32; o >= 1; o >>= 1) {
#pragma unroll
            for (int h = 0; h < NH; h++) lm[h] = fmaxf(lm[h], __shfl_down(lm[h], o, 64));
            eas += __shfl_down(eas, o, 64);
        }
        if (lane == 0) {
#pragma unroll
            for (int h = 0; h < NH; h++) wred[wid * 6 + h] = lm[h];
            wred[wid * 6 + 5] = eas;
        }
        __syncthreads();
        if (tid == 0) emean_sh = (wred[5] + wred[11] + wred[17]) / fmaxf((float)deg, 1.f);
        __syncthreads();
        if (tid < NH) {
            float m3 = fmaxf(fmaxf(wred[tid], wred[6 + tid]), wred[12 + tid]);
            float rs = lrelu(al_s[n * NH + tid] + sh_ad[tid] + emean_sh * sh_se[tid], 0.2f);
            w_sh[deg * NH + tid] = rs;
            sm[tid] = fmaxf(m3, rs);
        }
        if (tid == 0) { isrc_sh[deg] = n; ieid_sh[deg] = EE + n; }
        __syncthreads();

        float ls[NH] = {0.f, 0.f, 0.f, 0.f, 0.f};
        for (int i = tid; i < items; i += 192) {
#pragma unroll
            for (int h = 0; h < NH; h++) {
                float w = expf(w_sh[i * NH + h] - sm[h]);
                w_sh[i * NH + h] = w;
                ls[h] += w;
            }
        }
        for (int o = 32; o >= 1; o >>= 1) {
#pragma unroll
            for (int h = 0; h < NH; h++) ls[h] += __shfl_down(ls[h], o, 64);
        }
        if (lane == 0) {
#pragma unroll
            for (int h = 0; h < NH; h++) wred2[wid * 5 + h] = ls[h];
        }
        __syncthreads();
        if (tid < NH) sdinv[tid] = 1.f / (wred2[tid] + wred2[5 + tid] + wred2[10 + tid]);
        __syncthreads();

        for (int i = tid; i < items; i += 192) {
            int opos = ieid_sh[i];
#pragma unroll
            for (int h = 0; h < NH; h++) {
                float w = w_sh[i * NH + h] * sdinv[h];
                w_sh[i * NH + h] = w;
                alpha_out[(size_t)opos * NH + h] = w;
            }
        }
        __syncthreads();

        if (tid < HC) {
            int c = tid, hd = c >> 5;
            float acc = 0.f;
            for (int i = 0; i < items; i++) {
                acc += w_sh[i * NH + hd] * bf2f(hfeat[(size_t)isrc_sh[i] * HC + c]);
            }
            v = lrelu(acc + bias[c], 0.01f);
        }
    } else {
        float lm[NH];
#pragma unroll
        for (int h = 0; h < NH; h++) lm[h] = -3.0e38f;
        float eas = 0.f;
        for (int i = tid; i < deg; i += 192) {
            uint4 rec = erec[s0 + i];
            int src = (int)rec.x;
            float eav = __uint_as_float(rec.z);
            eas += eav;
#pragma unroll
            for (int h = 0; h < NH; h++) {
                float r = lrelu(al_s[src * NH + h] + adr[h] + eav * ser[h], 0.2f);
                lm[h] = fmaxf(lm[h], r);
            }
        }
        for (int o = 32; o >= 1; o >>= 1) {
#pragma unroll
            for (int h = 0; h < NH; h++) lm[h] = fmaxf(lm[h], __shfl_down(lm[h], o, 64));
            eas += __shfl_down(eas, o, 64);
        }
        if (lane == 0) {
#pragma unroll
            for (int h = 0; h < NH; h++) wred[wid * 6 + h] = lm[h];
            wred[wid * 6 + 5] = eas;
        }
        __syncthreads();
        if (tid == 0) emean_sh = (wred[5] + wred[11] + wred[17]) / fmaxf((float)deg, 1.f);
        __syncthreads();
        if (tid < NH) {
            float m3 = fmaxf(fmaxf(wred[tid], wred[6 + tid]), wred[12 + tid]);
            float rs = lrelu(al_s[n * NH + tid] + sh_ad[tid] + emean_sh * sh_se[tid], 0.2f);
            sm[tid] = fmaxf(m3, rs);
        }
        __syncthreads();

        float ls[NH] = {0.f, 0.f, 0.f, 0.f, 0.f};
        for (int i = tid; i < items; i += 192) {
            int src; float eav;
            if (i < deg) { uint4 rec = erec[s0 + i]; src = (int)rec.x; eav = __uint_as_float(rec.z); }
            else         { src = n; eav = emean_sh; }
#pragma unroll
            for (int h = 0; h < NH; h++) {
                float r = lrelu(al_s[src * NH + h] + adr[h] + eav * ser[h], 0.2f);
                ls[h] += expf(r - sm[h]);
            }
        }
        for (int o = 32; o >= 1; o >>= 1) {
#pragma unroll
            for (int h = 0; h < NH; h++) ls[h] += __shfl_down(ls[h], o, 64);
        }
        if (lane == 0) {
#pragma unroll
            for (int h = 0; h < NH; h++) wred2[wid * 5 + h] = ls[h];
        }
        __syncthreads();
        if (tid < NH) sdinv[tid] = 1.f / (wred2[tid] + wred2[5 + tid] + wred2[10 + tid]);
        __syncthreads();

        if (tid < HC) {
            int c = tid, hd = c >> 5;
            float mh = sm[hd], dinv = sdinv[hd], adh = sh_ad[hd], seh = sh_se[hd];
            float acc = 0.f;
            for (int i = 0; i < items; i++) {
                int src; float eav; int opos;
                if (i < deg) { uint4 rec = erec[s0 + i]; src = (int)rec.x; eav = __uint_as_float(rec.z); opos = (int)rec.y; }
                else         { src = n; eav = emean_sh; opos = EE + n; }
                float r = lrelu(al_s[src * NH + hd] + adh + eav * seh, 0.2f);
                float w = expf(r - mh) * dinv;
                if ((c & 31) == 0) alpha_out[(size_t)opos * NH + hd] = w;
                acc += w * bf2f(hfeat[(size_t)src * HC + c]);
            }
            v = lrelu(acc + bias[c], 0.01f);
        }
    }

    float p1 = (tid < HC) ? v : 0.f;
    float p2 = p1 * p1;
    for (int o = 32; o >= 1; o >>= 1) {
        p1 += __shfl_down(p1, o, 64);
        p2 += __shfl_down(p2, o, 64);
    }
    if (lane == 0) { wred[wid] = p1; wred[8 + wid] = p2; }
    __syncthreads();
    if (tid == 0) {
        float s1 = wred[0] + wred[1] + wred[2];
        float s2 = wred[8] + wred[9] + wred[10];
        float mean = s1 / (float)HC;
        float var = s2 / (float)HC - mean * mean;
        stat[0] = mean;
        stat[1] = rsqrtf(var + 1e-5f);
    }
    __syncthreads();
    if (tid < HC)
        x_out[(size_t)n * HC + tid] = (v - stat[0]) * stat[1] * g_ln[tid] + b_ln[tid];
}

// ---------------- mean-pool per graph (batch sorted -> contiguous row ranges)
__global__ __launch_bounds__(160) void pool_kernel(const float* __restrict__ x3,
                                                   const int* __restrict__ gstart,
                                                   const int* __restrict__ gcnt,
                                                   float* __restrict__ pooled) {
    int g = blockIdx.x;
    int c = threadIdx.x;
    int s = gstart[g], cnt = gcnt[g];
    float acc = 0.f;
    for (int r = 0; r < cnt; r++) acc += x3[(size_t)(s + r) * HC + c];
    pooled[g * HC + c] = acc / fmaxf((float)cnt, 1.f);
}

// ---------------------------------------------------------------------- launch
extern "C" void kernel_launch(void* const* d_in, const int* in_sizes, int n_in,
                              void* d_out, int out_size, void* d_ws, size_t ws_size,
                              hipStream_t stream) {
    const float* x    = (const float*)d_in[0];
    const int*   ei   = (const int*)d_in[1];
    const float* ea   = (const float*)d_in[2];
    const int*   batch= (const int*)d_in[3];
    const float* w1   = (const float*)d_in[4];
    const float* we1  = (const float*)d_in[5];
    const float* as1  = (const float*)d_in[6];
    const float* ad1  = (const float*)d_in[7];
    const float* ae1  = (const float*)d_in[8];
    const float* b1   = (const float*)d_in[9];
    const float* w2   = (const float*)d_in[10];
    const float* we2  = (const float*)d_in[11];
    const float* as2  = (const float*)d_in[12];
    const float* ad2  = (const float*)d_in[13];
    const float* ae2  = (const float*)d_in[14];
    const float* b2   = (const float*)d_in[15];
    const float* ln1g = (const float*)d_in[16];
    const float* ln1b = (const float*)d_in[17];
    const float* ln2g = (const float*)d_in[18];
    const float* ln2b = (const float*)d_in[19];
    const float* mw   = (const float*)d_in[20];
    const float* mb   = (const float*)d_in[21];

    float* out = (float*)d_out;
    float* x12 = out;
    float* pooled_out = out + (size_t)NN * HC;
    float* a1 = pooled_out + NG * HC;
    float* a2 = a1 + (size_t)(EE + NN) * NH;

    char* wp = (char*)d_ws;
    auto alloc = [&](size_t bytes) {
        void* p = (void*)wp;
        wp += (bytes + 255) & ~(size_t)255;
        return p;
    };
    unsigned short* hbuf16 = (unsigned short*)alloc((size_t)NN * HC * 2);  // 16 MB
    uint4* erec  = (uint4*)alloc((size_t)EE * 16);                          // 12.8 MB
    unsigned short* base_g = hbuf16;            // overlay: dead before gemm1
    unsigned*       hist_g = (unsigned*)erec;   // overlay: dead before scatter
    float* als   = (float*)alloc((size_t)NN * NH * 4);
    float* ald   = (float*)alloc((size_t)NN * NH * 4);
    int*   deg   = (int*)alloc((size_t)NN * 4);
    int*   soff  = (int*)alloc((size_t)(NN + 1) * 4);
    float* sbuf  = (float*)alloc(64);
    int*   gcnt  = (int*)alloc((size_t)NG * 4);
    int*   gstart= (int*)alloc((size_t)NG * 4);
    int*   bsum  = (int*)alloc(256 * 4);
    int*   boff  = (int*)alloc(256 * 4);

    prep_kernel<<<1, 64, 0, stream>>>(batch, gstart, gcnt);
    hist_kernel<<<NB, 256, 0, stream>>>(ei, hist_g);
    sscan_kernel<<<49, 256, 0, stream>>>(hist_g, base_g, deg);
    scan1_kernel<<<196, 256, 0, stream>>>(deg, bsum);
    scan2_kernel<<<1, 256, 0, stream>>>(bsum, boff);
    scan3_kernel<<<196, 256, 0, stream>>>(deg, boff, soff);
    scatter_kernel<<<NB, 256, 0, stream>>>(ei, ea, base_g, soff, erec);
    preps_kernel<<<1, 64, 0, stream>>>(we1, ae1, we2, ae2, sbuf);

    gemm_kernel<128, true><<<782, 160, 0, stream>>>(x, w1, as1, ad1, nullptr,
                                                    hbuf16, nullptr, als, ald);
    aggregate_kernel<<<NN, 192, 0, stream>>>(soff, erec, hbuf16, als, ald,
                                             sbuf, b1, ln1g, ln1b, a1, x12);

    gemm_kernel<160, true><<<782, 160, 0, stream>>>(x12, w2, as2, ad2, nullptr,
                                                    hbuf16, nullptr, als, ald);
    aggregate_kernel<<<NN, 192, 0, stream>>>(soff, erec, hbuf16, als, ald,
                                             sbuf + 5, b2, ln2g, ln2b, a2, x12);

    gemm_kernel<160, false><<<782, 160, 0, stream>>>(x12, mw, nullptr, nullptr, mb,
                                                     nullptr, out, nullptr, nullptr);
    pool_kernel<<<NG, HC, 0, stream>>>(out, gstart, gcnt, pooled_out);
}

// Round 5
// 851.322 us; speedup vs baseline: 1.2086x; 1.2086x over previous
//
#include <hip/hip_runtime.h>
#include <math.h>

#define NN 50000
#define EE 800000
#define FIN 128
#define NH 5
#define HC 160
#define NG 64
#define CHUNK 384
#define NB 160
#define EPB 5000
#define NW 12500
#define NPART 16

__device__ __forceinline__ float lrelu(float x, float s) { return x >= 0.f ? x : s * x; }

__device__ __forceinline__ unsigned short f2bf(float x) {
    unsigned u = __float_as_uint(x);
    unsigned r = (u + 0x7fffu + ((u >> 16) & 1u)) >> 16;
    return (unsigned short)r;
}
__device__ __forceinline__ float bf2f(unsigned short b) {
    return __uint_as_float(((unsigned)b) << 16);
}

// ------- zero psum + per-graph row ranges via binary search (batch sorted)
__global__ void prep_kernel(const int* __restrict__ batch, int* gstart, int* gcnt,
                            float* psum) {
    int i = blockIdx.x * 256 + threadIdx.x;
    if (i < NG * HC) psum[i] = 0.f;
    if (i < NG) {
        int lo = 0, hi = NN;
        while (lo < hi) { int m = (lo + hi) >> 1; if (batch[m] < i) lo = m + 1; else hi = m; }
        int s = lo;
        lo = 0; hi = NN;
        int g1 = i + 1;
        while (lo < hi) { int m = (lo + hi) >> 1; if (batch[m] < g1) lo = m + 1; else hi = m; }
        gstart[i] = s;
        gcnt[i] = lo - s;
    }
}

// ---------------- per-block LDS histogram of dst (byte-packed, no global atomics)
__global__ __launch_bounds__(256) void hist_kernel(const int* __restrict__ ei,
                                                   unsigned* __restrict__ hist_g) {
    __shared__ unsigned lh[NW];
    int b = blockIdx.x, tid = threadIdx.x;
    for (int w = tid; w < NW; w += 256) lh[w] = 0;
    __syncthreads();
    const int* dstp = ei + EE + b * EPB;
    for (int i = tid; i < EPB; i += 256) {
        int d = dstp[i];
        atomicAdd(&lh[d >> 2], 1u << ((d & 3) * 8));
    }
    __syncthreads();
    unsigned* outp = hist_g + (size_t)b * NW;
    for (int w = tid; w < NW; w += 256) outp[w] = lh[w];
}

// ---------------- column scan over blocks: per-(block,bin) base + total deg
__global__ void sscan_kernel(const unsigned* __restrict__ hist_g,
                             unsigned short* __restrict__ base_g, int* __restrict__ deg) {
    int w = blockIdx.x * 256 + threadIdx.x;
    if (w >= NW) return;
    unsigned r0 = 0, r1 = 0, r2 = 0, r3 = 0;
    for (int b = 0; b < NB; b++) {
        unsigned x = hist_g[(size_t)b * NW + w];
        uint2 st;
        st.x = r0 | (r1 << 16);
        st.y = r2 | (r3 << 16);
        *reinterpret_cast<uint2*>(&base_g[(size_t)b * NN + 4 * w]) = st;
        r0 += x & 0xffu; r1 += (x >> 8) & 0xffu; r2 += (x >> 16) & 0xffu; r3 += (x >> 24) & 0xffu;
    }
    uint4 dv; dv.x = r0; dv.y = r1; dv.z = r2; dv.w = r3;
    *reinterpret_cast<uint4*>(&deg[4 * w]) = dv;
}

// ------------------------------------------------------- 3-phase parallel scan
__global__ void scan1_kernel(const int* __restrict__ deg, int* bsum) {
    __shared__ int ws[4];
    int tid = threadIdx.x, lane = tid & 63, wid = tid >> 6;
    int i = blockIdx.x * 256 + tid;
    int v = (i < NN) ? deg[i] : 0;
    for (int o = 32; o >= 1; o >>= 1) v += __shfl_down(v, o, 64);
    if (lane == 0) ws[wid] = v;
    __syncthreads();
    if (tid == 0) bsum[blockIdx.x] = ws[0] + ws[1] + ws[2] + ws[3];
}

__global__ void scan2_kernel(int* bsum, int* boff) {
    __shared__ int ws[4];
    int tid = threadIdx.x, lane = tid & 63, wid = tid >> 6;
    int v = (tid < 196) ? bsum[tid] : 0;
    int x = v;
    for (int o = 1; o < 64; o <<= 1) {
        int t = __shfl_up(x, o, 64);
        if (lane >= o) x += t;
    }
    if (lane == 63) ws[wid] = x;
    __syncthreads();
    if (tid == 0) {
        int acc = 0;
        for (int w = 0; w < 4; w++) { int t = ws[w]; ws[w] = acc; acc += t; }
    }
    __syncthreads();
    if (tid < 196) boff[tid] = x + ws[wid] - v;
}

__global__ void scan3_kernel(const int* __restrict__ deg, const int* __restrict__ boff,
                             int* off) {
    __shared__ int ws[4];
    int tid = threadIdx.x, lane = tid & 63, wid = tid >> 6;
    int i = blockIdx.x * 256 + tid;
    int v = (i < NN) ? deg[i] : 0;
    int x = v;
    for (int o = 1; o < 64; o <<= 1) {
        int t = __shfl_up(x, o, 64);
        if (lane >= o) x += t;
    }
    if (lane == 63) ws[wid] = x;
    __syncthreads();
    if (tid == 0) {
        int acc = 0;
        for (int w = 0; w < 4; w++) { int t = ws[w]; ws[w] = acc; acc += t; }
    }
    __syncthreads();
    int incl = x + ws[wid] + boff[blockIdx.x];
    if (i < NN) off[i + 1] = incl;
    if (i == 0) off[0] = 0;
}

// ---------------- rank via LDS + write packed edge record (no global atomics)
__global__ __launch_bounds__(256) void scatter_kernel(const int* __restrict__ ei,
                                                      const float* __restrict__ ea,
                                                      const unsigned short* __restrict__ base_g,
                                                      const int* __restrict__ soff,
                                                      uint4* __restrict__ erec) {
    __shared__ unsigned lc[NW];
    int b = blockIdx.x, tid = threadIdx.x;
    for (int w = tid; w < NW; w += 256) lc[w] = 0;
    __syncthreads();
    int e0 = b * EPB;
    const unsigned short* brow = base_g + (size_t)b * NN;
    for (int i = tid; i < EPB; i += 256) {
        int e = e0 + i;
        int d = ei[EE + e];
        int sh = (d & 3) * 8;
        unsigned old = atomicAdd(&lc[d >> 2], 1u << sh);
        int r = (int)((old >> sh) & 0xffu);
        int pos = soff[d] + (int)brow[d] + r;
        uint4 rec;
        rec.x = (unsigned)ei[e];
        rec.y = (unsigned)e;
        rec.z = __float_as_uint(ea[e]);
        rec.w = 0;
        erec[pos] = rec;
    }
}

// -------------------------------------- s[h] = dot(we[h*32: ], ae[h]) per layer
__global__ void preps_kernel(const float* we1, const float* ae1,
                             const float* we2, const float* ae2, float* s_out) {
    int tid = threadIdx.x;
    if (tid < 10) {
        const float* we = (tid < 5) ? we1 : we2;
        const float* ae = (tid < 5) ? ae1 : ae2;
        int h = tid % 5;
        float s = 0.f;
        for (int c = 0; c < 32; c++) s += we[h * 32 + c] * ae[h * 32 + c];
        s_out[tid] = s;
    }
}

#define ROWFMA(i, s) { acc[i].x += (s)*w4.x; acc[i].y += (s)*w4.y; acc[i].z += (s)*w4.z; acc[i].w += (s)*w4.w; }

// ---- h = A @ W, tile M=64, thread = 16 rows x 4 cols.
// BF: bf16 out + att-dot epilogue. !BF: fp32 out with bias+lrelu (merge MLP).
template <int K, bool BF>
__global__ __launch_bounds__(160) void gemm_kernel(const float* __restrict__ A,
                                                   const float* __restrict__ W,
                                                   const float* __restrict__ a_s,
                                                   const float* __restrict__ a_d,
                                                   const float* __restrict__ bias,
                                                   unsigned short* __restrict__ out_bf,
                                                   float* __restrict__ out_f,
                                                   float* al_s, float* al_d) {
    const int SUBSTRIDE = K * 16 + 4;
    __shared__ float smem[10256];
    int t = threadIdx.x;
    int sub = t / 40, cg = t - sub * 40;
    int base = blockIdx.x * 64;

    for (int idx = t; idx < 64 * K; idx += 160) {
        int r = idx / K, k = idx - r * K;
        int row = base + r;
        float v = (row < NN) ? A[(size_t)row * K + k] : 0.f;
        smem[(r >> 4) * SUBSTRIDE + k * 16 + (r & 15)] = v;
    }
    __syncthreads();

    float4 acc[16];
#pragma unroll
    for (int r = 0; r < 16; r++) acc[r] = make_float4(0.f, 0.f, 0.f, 0.f);

    const float* Wp = W + cg * 4;
    const float* xbase = &smem[sub * SUBSTRIDE];
    for (int k = 0; k < K; k++) {
        float4 w4 = *reinterpret_cast<const float4*>(Wp + (size_t)k * HC);
        const float4* xr = reinterpret_cast<const float4*>(xbase + k * 16);
        float4 q0 = xr[0], q1 = xr[1], q2 = xr[2], q3 = xr[3];
        ROWFMA(0, q0.x) ROWFMA(1, q0.y) ROWFMA(2, q0.z) ROWFMA(3, q0.w)
        ROWFMA(4, q1.x) ROWFMA(5, q1.y) ROWFMA(6, q1.z) ROWFMA(7, q1.w)
        ROWFMA(8, q2.x) ROWFMA(9, q2.y) ROWFMA(10, q2.z) ROWFMA(11, q2.w)
        ROWFMA(12, q3.x) ROWFMA(13, q3.y) ROWFMA(14, q3.z) ROWFMA(15, q3.w)
    }

    if (!BF) {
        float4 b4 = *reinterpret_cast<const float4*>(bias + cg * 4);
#pragma unroll
        for (int r = 0; r < 16; r++) {
            int row = base + sub * 16 + r;
            if (row < NN) {
                float4 o;
                o.x = lrelu(acc[r].x + b4.x, 0.01f);
                o.y = lrelu(acc[r].y + b4.y, 0.01f);
                o.z = lrelu(acc[r].z + b4.z, 0.01f);
                o.w = lrelu(acc[r].w + b4.w, 0.01f);
                *reinterpret_cast<float4*>(&out_f[(size_t)row * HC + cg * 4]) = o;
            }
        }
        return;
    }

#pragma unroll
    for (int r = 0; r < 16; r++) {
        int row = base + sub * 16 + r;
        if (row < NN) {
            uint2 p;
            p.x = (unsigned)f2bf(acc[r].x) | ((unsigned)f2bf(acc[r].y) << 16);
            p.y = (unsigned)f2bf(acc[r].z) | ((unsigned)f2bf(acc[r].w) << 16);
            *reinterpret_cast<uint2*>(&out_bf[(size_t)row * HC + cg * 4]) = p;
        }
    }

    __syncthreads();
    float* hs = smem;
#pragma unroll
    for (int r = 0; r < 16; r++) {
        *reinterpret_cast<float4*>(&hs[(sub * 16 + r) * HC + cg * 4]) = acc[r];
    }
    __syncthreads();
    for (int task = t; task < 640; task += 160) {
        int r = task / 10, rem = task - r * 10;
        int hd = rem >> 1, sd = rem & 1;
        int row = base + r;
        if (row < NN) {
            const float* av = sd ? a_d : a_s;
            float s = 0.f;
#pragma unroll
            for (int c = 0; c < 32; c++) s += hs[r * HC + hd * 32 + c] * av[hd * 32 + c];
            float* dst = sd ? al_d : al_s;
            dst[row * NH + hd] = s;
        }
    }
}

// ------------- per-node: segment softmax + weighted gather + bias/lrelu/LN
__global__ __launch_bounds__(192) void aggregate_kernel(
    const int* __restrict__ soff, const uint4* __restrict__ erec,
    const unsigned short* __restrict__ hfeat, const float* __restrict__ al_s,
    const float* __restrict__ al_d, const float* __restrict__ s_e,
    const float* __restrict__ bias, const float* __restrict__ g_ln,
    const float* __restrict__ b_ln,
    float* __restrict__ alpha_out, float* __restrict__ x_out) {
    int n = blockIdx.x;
    int tid = threadIdx.x;
    int lane = tid & 63, wid = tid >> 6;
    int s0 = soff[n];
    int deg = soff[n + 1] - s0;
    int items = deg + 1;

    __shared__ float w_sh[CHUNK * NH];
    __shared__ int isrc_sh[CHUNK];
    __shared__ int ieid_sh[CHUNK];
    __shared__ float sm[NH], sdinv[NH];
    __shared__ float sh_ad[NH], sh_se[NH];
    __shared__ float wred[18], wred2[15];
    __shared__ float stat[2];
    __shared__ float emean_sh;

    if (tid < NH) { sh_ad[tid] = al_d[n * NH + tid]; sh_se[tid] = s_e[tid]; }
    __syncthreads();
    float adr[NH], ser[NH];
#pragma unroll
    for (int h = 0; h < NH; h++) { adr[h] = sh_ad[h]; ser[h] = sh_se[h]; }

    float v = 0.f;

    if (items <= CHUNK) {
        float lm[NH];
#pragma unroll
        for (int h = 0; h < NH; h++) lm[h] = -3.0e38f;
        float eas = 0.f;
        for (int i = tid; i < deg; i += 192) {
            uint4 rec = erec[s0 + i];
            int src = (int)rec.x;
            float eav = __uint_as_float(rec.z);
            isrc_sh[i] = src;
            ieid_sh[i] = (int)rec.y;
            eas += eav;
#pragma unroll
            for (int h = 0; h < NH; h++) {
                float r = lrelu(al_s[src * NH + h] + adr[h] + eav * ser[h], 0.2f);
                w_sh[i * NH + h] = r;
                lm[h] = fmaxf(lm[h], r);
            }
        }
        for (int o = 32; o >= 1; o >>= 1) {
#pragma unroll
            for (int h = 0; h < NH; h++) lm[h] = fmaxf(lm[h], __shfl_down(lm[h], o, 64));
            eas += __shfl_down(eas, o, 64);
        }
        if (lane == 0) {
#pragma unroll
            for (int h = 0; h < NH; h++) wred[wid * 6 + h] = lm[h];
            wred[wid * 6 + 5] = eas;
        }
        __syncthreads();
        if (tid == 0) emean_sh = (wred[5] + wred[11] + wred[17]) / fmaxf((float)deg, 1.f);
        __syncthreads();
        if (tid < NH) {
            float m3 = fmaxf(fmaxf(wred[tid], wred[6 + tid]), wred[12 + tid]);
            float rs = lrelu(al_s[n * NH + tid] + sh_ad[tid] + emean_sh * sh_se[tid], 0.2f);
            w_sh[deg * NH + tid] = rs;
            sm[tid] = fmaxf(m3, rs);
        }
        if (tid == 0) { isrc_sh[deg] = n; ieid_sh[deg] = EE + n; }
        __syncthreads();

        float ls[NH] = {0.f, 0.f, 0.f, 0.f, 0.f};
        for (int i = tid; i < items; i += 192) {
#pragma unroll
            for (int h = 0; h < NH; h++) {
                float w = expf(w_sh[i * NH + h] - sm[h]);
                w_sh[i * NH + h] = w;
                ls[h] += w;
            }
        }
        for (int o = 32; o >= 1; o >>= 1) {
#pragma unroll
            for (int h = 0; h < NH; h++) ls[h] += __shfl_down(ls[h], o, 64);
        }
        if (lane == 0) {
#pragma unroll
            for (int h = 0; h < NH; h++) wred2[wid * 5 + h] = ls[h];
        }
        __syncthreads();
        if (tid < NH) sdinv[tid] = 1.f / (wred2[tid] + wred2[5 + tid] + wred2[10 + tid]);
        __syncthreads();

        for (int i = tid; i < items; i += 192) {
            int opos = ieid_sh[i];
#pragma unroll
            for (int h = 0; h < NH; h++) {
                float w = w_sh[i * NH + h] * sdinv[h];
                w_sh[i * NH + h] = w;
                alpha_out[(size_t)opos * NH + h] = w;
            }
        }
        __syncthreads();

        if (tid < HC) {
            int c = tid, hd = c >> 5;
            float acc = 0.f;
            for (int i = 0; i < items; i++) {
                acc += w_sh[i * NH + hd] * bf2f(hfeat[(size_t)isrc_sh[i] * HC + c]);
            }
            v = lrelu(acc + bias[c], 0.01f);
        }
    } else {
        float lm[NH];
#pragma unroll
        for (int h = 0; h < NH; h++) lm[h] = -3.0e38f;
        float eas = 0.f;
        for (int i = tid; i < deg; i += 192) {
            uint4 rec = erec[s0 + i];
            int src = (int)rec.x;
            float eav = __uint_as_float(rec.z);
            eas += eav;
#pragma unroll
            for (int h = 0; h < NH; h++) {
                float r = lrelu(al_s[src * NH + h] + adr[h] + eav * ser[h], 0.2f);
                lm[h] = fmaxf(lm[h], r);
            }
        }
        for (int o = 32; o >= 1; o >>= 1) {
#pragma unroll
            for (int h = 0; h < NH; h++) lm[h] = fmaxf(lm[h], __shfl_down(lm[h], o, 64));
            eas += __shfl_down(eas, o, 64);
        }
        if (lane == 0) {
#pragma unroll
            for (int h = 0; h < NH; h++) wred[wid * 6 + h] = lm[h];
            wred[wid * 6 + 5] = eas;
        }
        __syncthreads();
        if (tid == 0) emean_sh = (wred[5] + wred[11] + wred[17]) / fmaxf((float)deg, 1.f);
        __syncthreads();
        if (tid < NH) {
            float m3 = fmaxf(fmaxf(wred[tid], wred[6 + tid]), wred[12 + tid]);
            float rs = lrelu(al_s[n * NH + tid] + sh_ad[tid] + emean_sh * sh_se[tid], 0.2f);
            sm[tid] = fmaxf(m3, rs);
        }
        __syncthreads();

        float ls[NH] = {0.f, 0.f, 0.f, 0.f, 0.f};
        for (int i = tid; i < items; i += 192) {
            int src; float eav;
            if (i < deg) { uint4 rec = erec[s0 + i]; src = (int)rec.x; eav = __uint_as_float(rec.z); }
            else         { src = n; eav = emean_sh; }
#pragma unroll
            for (int h = 0; h < NH; h++) {
                float r = lrelu(al_s[src * NH + h] + adr[h] + eav * ser[h], 0.2f);
                ls[h] += expf(r - sm[h]);
            }
        }
        for (int o = 32; o >= 1; o >>= 1) {
#pragma unroll
            for (int h = 0; h < NH; h++) ls[h] += __shfl_down(ls[h], o, 64);
        }
        if (lane == 0) {
#pragma unroll
            for (int h = 0; h < NH; h++) wred2[wid * 5 + h] = ls[h];
        }
        __syncthreads();
        if (tid < NH) sdinv[tid] = 1.f / (wred2[tid] + wred2[5 + tid] + wred2[10 + tid]);
        __syncthreads();

        if (tid < HC) {
            int c = tid, hd = c >> 5;
            float mh = sm[hd], dinv = sdinv[hd], adh = sh_ad[hd], seh = sh_se[hd];
            float acc = 0.f;
            for (int i = 0; i < items; i++) {
                int src; float eav; int opos;
                if (i < deg) { uint4 rec = erec[s0 + i]; src = (int)rec.x; eav = __uint_as_float(rec.z); opos = (int)rec.y; }
                else         { src = n; eav = emean_sh; opos = EE + n; }
                float r = lrelu(al_s[src * NH + hd] + adh + eav * seh, 0.2f);
                float w = expf(r - mh) * dinv;
                if ((c & 31) == 0) alpha_out[(size_t)opos * NH + hd] = w;
                acc += w * bf2f(hfeat[(size_t)src * HC + c]);
            }
            v = lrelu(acc + bias[c], 0.01f);
        }
    }

    float p1 = (tid < HC) ? v : 0.f;
    float p2 = p1 * p1;
    for (int o = 32; o >= 1; o >>= 1) {
        p1 += __shfl_down(p1, o, 64);
        p2 += __shfl_down(p2, o, 64);
    }
    if (lane == 0) { wred[wid] = p1; wred[8 + wid] = p2; }
    __syncthreads();
    if (tid == 0) {
        float s1 = wred[0] + wred[1] + wred[2];
        float s2 = wred[8] + wred[9] + wred[10];
        float mean = s1 / (float)HC;
        float var = s2 / (float)HC - mean * mean;
        stat[0] = mean;
        stat[1] = rsqrtf(var + 1e-5f);
    }
    __syncthreads();
    if (tid < HC)
        x_out[(size_t)n * HC + tid] = (v - stat[0]) * stat[1] * g_ln[tid] + b_ln[tid];
}

// ---- mean-pool stage 1: 16 partitions per graph, one atomicAdd per (block,ch)
__global__ __launch_bounds__(160) void pool1_kernel(const float* __restrict__ x3,
                                                    const int* __restrict__ gstart,
                                                    const int* __restrict__ gcnt,
                                                    float* __restrict__ psum) {
    int g = blockIdx.x / NPART;
    int part = blockIdx.x - g * NPART;
    int c = threadIdx.x;
    int s = gstart[g], cnt = gcnt[g];
    int chunk = (cnt + NPART - 1) / NPART;
    int r0 = part * chunk;
    int r1 = min(cnt, r0 + chunk);
    if (r0 >= r1) return;
    float acc = 0.f;
    for (int r = r0; r < r1; r++) acc += x3[(size_t)(s + r) * HC + c];
    atomicAdd(&psum[g * HC + c], acc);
}

__global__ void pooldiv_kernel(const float* __restrict__ psum, const int* __restrict__ gcnt,
                               float* __restrict__ pooled_out) {
    int i = blockIdx.x * 256 + threadIdx.x;
    if (i < NG * HC) pooled_out[i] = psum[i] / fmaxf((float)gcnt[i / HC], 1.f);
}

// ---------------------------------------------------------------------- launch
extern "C" void kernel_launch(void* const* d_in, const int* in_sizes, int n_in,
                              void* d_out, int out_size, void* d_ws, size_t ws_size,
                              hipStream_t stream) {
    const float* x    = (const float*)d_in[0];
    const int*   ei   = (const int*)d_in[1];
    const float* ea   = (const float*)d_in[2];
    const int*   batch= (const int*)d_in[3];
    const float* w1   = (const float*)d_in[4];
    const float* we1  = (const float*)d_in[5];
    const float* as1  = (const float*)d_in[6];
    const float* ad1  = (const float*)d_in[7];
    const float* ae1  = (const float*)d_in[8];
    const float* b1   = (const float*)d_in[9];
    const float* w2   = (const float*)d_in[10];
    const float* we2  = (const float*)d_in[11];
    const float* as2  = (const float*)d_in[12];
    const float* ad2  = (const float*)d_in[13];
    const float* ae2  = (const float*)d_in[14];
    const float* b2   = (const float*)d_in[15];
    const float* ln1g = (const float*)d_in[16];
    const float* ln1b = (const float*)d_in[17];
    const float* ln2g = (const float*)d_in[18];
    const float* ln2b = (const float*)d_in[19];
    const float* mw   = (const float*)d_in[20];
    const float* mb   = (const float*)d_in[21];

    float* out = (float*)d_out;
    float* x12 = out;
    float* pooled_out = out + (size_t)NN * HC;
    float* a1 = pooled_out + NG * HC;
    float* a2 = a1 + (size_t)(EE + NN) * NH;

    char* wp = (char*)d_ws;
    auto alloc = [&](size_t bytes) {
        void* p = (void*)wp;
        wp += (bytes + 255) & ~(size_t)255;
        return p;
    };
    unsigned short* hbuf16 = (unsigned short*)alloc((size_t)NN * HC * 2);  // 16 MB
    uint4* erec  = (uint4*)alloc((size_t)EE * 16);                          // 12.8 MB
    unsigned short* base_g = hbuf16;            // overlay: dead before gemm1
    unsigned*       hist_g = (unsigned*)erec;   // overlay: dead before scatter
    float* als   = (float*)alloc((size_t)NN * NH * 4);
    float* ald   = (float*)alloc((size_t)NN * NH * 4);
    int*   deg   = (int*)alloc((size_t)NN * 4);
    int*   soff  = (int*)alloc((size_t)(NN + 1) * 4);
    float* sbuf  = (float*)alloc(64);
    float* psum  = (float*)alloc((size_t)NG * HC * 4);
    int*   gcnt  = (int*)alloc((size_t)NG * 4);
    int*   gstart= (int*)alloc((size_t)NG * 4);
    int*   bsum  = (int*)alloc(256 * 4);
    int*   boff  = (int*)alloc(256 * 4);

    prep_kernel<<<40, 256, 0, stream>>>(batch, gstart, gcnt, psum);
    hist_kernel<<<NB, 256, 0, stream>>>(ei, hist_g);
    sscan_kernel<<<49, 256, 0, stream>>>(hist_g, base_g, deg);
    scan1_kernel<<<196, 256, 0, stream>>>(deg, bsum);
    scan2_kernel<<<1, 256, 0, stream>>>(bsum, boff);
    scan3_kernel<<<196, 256, 0, stream>>>(deg, boff, soff);
    scatter_kernel<<<NB, 256, 0, stream>>>(ei, ea, base_g, soff, erec);
    preps_kernel<<<1, 64, 0, stream>>>(we1, ae1, we2, ae2, sbuf);

    gemm_kernel<128, true><<<782, 160, 0, stream>>>(x, w1, as1, ad1, nullptr,
                                                    hbuf16, nullptr, als, ald);
    aggregate_kernel<<<NN, 192, 0, stream>>>(soff, erec, hbuf16, als, ald,
                                             sbuf, b1, ln1g, ln1b, a1, x12);

    gemm_kernel<160, true><<<782, 160, 0, stream>>>(x12, w2, as2, ad2, nullptr,
                                                    hbuf16, nullptr, als, ald);
    aggregate_kernel<<<NN, 192, 0, stream>>>(soff, erec, hbuf16, als, ald,
                                             sbuf + 5, b2, ln2g, ln2b, a2, x12);

    gemm_kernel<160, false><<<782, 160, 0, stream>>>(x12, mw, nullptr, nullptr, mb,
                                                     nullptr, out, nullptr, nullptr);
    pool1_kernel<<<NG * NPART, 160, 0, stream>>>(out, gstart, gcnt, psum);
    pooldiv_kernel<<<40, 256, 0, stream>>>(psum, gcnt, pooled_out);
}

// Round 6
// 723.238 us; speedup vs baseline: 1.4227x; 1.1771x over previous
//
#include <hip/hip_runtime.h>
#include <math.h>

#define NN 50000
#define EE 800000
#define FIN 128
#define NH 5
#define HC 160
#define NG 64
#define NB 160
#define EPB 5000
#define NW 12500
#define NPART 16

__device__ __forceinline__ float lrelu(float x, float s) { return x >= 0.f ? x : s * x; }

__device__ __forceinline__ unsigned short f2bf(float x) {
    unsigned u = __float_as_uint(x);
    unsigned r = (u + 0x7fffu + ((u >> 16) & 1u)) >> 16;
    return (unsigned short)r;
}
__device__ __forceinline__ float bf2f(unsigned short b) {
    return __uint_as_float(((unsigned)b) << 16);
}

// ------- zero psum + per-graph row ranges via binary search (batch sorted)
__global__ void prep_kernel(const int* __restrict__ batch, int* gstart, int* gcnt,
                            float* psum) {
    int i = blockIdx.x * 256 + threadIdx.x;
    if (i < NG * HC) psum[i] = 0.f;
    if (i < NG) {
        int lo = 0, hi = NN;
        while (lo < hi) { int m = (lo + hi) >> 1; if (batch[m] < i) lo = m + 1; else hi = m; }
        int s = lo;
        lo = 0; hi = NN;
        int g1 = i + 1;
        while (lo < hi) { int m = (lo + hi) >> 1; if (batch[m] < g1) lo = m + 1; else hi = m; }
        gstart[i] = s;
        gcnt[i] = lo - s;
    }
}

// ---------------- per-block LDS histogram of dst (byte-packed, no global atomics)
__global__ __launch_bounds__(256) void hist_kernel(const int* __restrict__ ei,
                                                   unsigned* __restrict__ hist_g) {
    __shared__ unsigned lh[NW];
    int b = blockIdx.x, tid = threadIdx.x;
    for (int w = tid; w < NW; w += 256) lh[w] = 0;
    __syncthreads();
    const int* dstp = ei + EE + b * EPB;
    for (int i = tid; i < EPB; i += 256) {
        int d = dstp[i];
        atomicAdd(&lh[d >> 2], 1u << ((d & 3) * 8));
    }
    __syncthreads();
    unsigned* outp = hist_g + (size_t)b * NW;
    for (int w = tid; w < NW; w += 256) outp[w] = lh[w];
}

// ---------------- column scan over blocks: per-(block,bin) base + total deg
__global__ void sscan_kernel(const unsigned* __restrict__ hist_g,
                             unsigned short* __restrict__ base_g, int* __restrict__ deg) {
    int w = blockIdx.x * 256 + threadIdx.x;
    if (w >= NW) return;
    unsigned r0 = 0, r1 = 0, r2 = 0, r3 = 0;
    for (int b = 0; b < NB; b++) {
        unsigned x = hist_g[(size_t)b * NW + w];
        uint2 st;
        st.x = r0 | (r1 << 16);
        st.y = r2 | (r3 << 16);
        *reinterpret_cast<uint2*>(&base_g[(size_t)b * NN + 4 * w]) = st;
        r0 += x & 0xffu; r1 += (x >> 8) & 0xffu; r2 += (x >> 16) & 0xffu; r3 += (x >> 24) & 0xffu;
    }
    uint4 dv; dv.x = r0; dv.y = r1; dv.z = r2; dv.w = r3;
    *reinterpret_cast<uint4*>(&deg[4 * w]) = dv;
}

// ------------------------------------------------------- 3-phase parallel scan
__global__ void scan1_kernel(const int* __restrict__ deg, int* bsum) {
    __shared__ int ws[4];
    int tid = threadIdx.x, lane = tid & 63, wid = tid >> 6;
    int i = blockIdx.x * 256 + tid;
    int v = (i < NN) ? deg[i] : 0;
    for (int o = 32; o >= 1; o >>= 1) v += __shfl_down(v, o, 64);
    if (lane == 0) ws[wid] = v;
    __syncthreads();
    if (tid == 0) bsum[blockIdx.x] = ws[0] + ws[1] + ws[2] + ws[3];
}

__global__ void scan2_kernel(int* bsum, int* boff) {
    __shared__ int ws[4];
    int tid = threadIdx.x, lane = tid & 63, wid = tid >> 6;
    int v = (tid < 196) ? bsum[tid] : 0;
    int x = v;
    for (int o = 1; o < 64; o <<= 1) {
        int t = __shfl_up(x, o, 64);
        if (lane >= o) x += t;
    }
    if (lane == 63) ws[wid] = x;
    __syncthreads();
    if (tid == 0) {
        int acc = 0;
        for (int w = 0; w < 4; w++) { int t = ws[w]; ws[w] = acc; acc += t; }
    }
    __syncthreads();
    if (tid < 196) boff[tid] = x + ws[wid] - v;
}

__global__ void scan3_kernel(const int* __restrict__ deg, const int* __restrict__ boff,
                             int* off) {
    __shared__ int ws[4];
    int tid = threadIdx.x, lane = tid & 63, wid = tid >> 6;
    int i = blockIdx.x * 256 + tid;
    int v = (i < NN) ? deg[i] : 0;
    int x = v;
    for (int o = 1; o < 64; o <<= 1) {
        int t = __shfl_up(x, o, 64);
        if (lane >= o) x += t;
    }
    if (lane == 63) ws[wid] = x;
    __syncthreads();
    if (tid == 0) {
        int acc = 0;
        for (int w = 0; w < 4; w++) { int t = ws[w]; ws[w] = acc; acc += t; }
    }
    __syncthreads();
    int incl = x + ws[wid] + boff[blockIdx.x];
    if (i < NN) off[i + 1] = incl;
    if (i == 0) off[0] = 0;
}

// ---------------- rank via LDS + write packed edge record (no global atomics)
__global__ __launch_bounds__(256) void scatter_kernel(const int* __restrict__ ei,
                                                      const float* __restrict__ ea,
                                                      const unsigned short* __restrict__ base_g,
                                                      const int* __restrict__ soff,
                                                      uint4* __restrict__ erec) {
    __shared__ unsigned lc[NW];
    int b = blockIdx.x, tid = threadIdx.x;
    for (int w = tid; w < NW; w += 256) lc[w] = 0;
    __syncthreads();
    int e0 = b * EPB;
    const unsigned short* brow = base_g + (size_t)b * NN;
    for (int i = tid; i < EPB; i += 256) {
        int e = e0 + i;
        int d = ei[EE + e];
        int sh = (d & 3) * 8;
        unsigned old = atomicAdd(&lc[d >> 2], 1u << sh);
        int r = (int)((old >> sh) & 0xffu);
        int pos = soff[d] + (int)brow[d] + r;
        uint4 rec;
        rec.x = (unsigned)ei[e];
        rec.y = (unsigned)e;
        rec.z = __float_as_uint(ea[e]);
        rec.w = 0;
        erec[pos] = rec;
    }
}

// -------------------------------------- s[h] = dot(we[h*32: ], ae[h]) per layer
__global__ void preps_kernel(const float* we1, const float* ae1,
                             const float* we2, const float* ae2, float* s_out) {
    int tid = threadIdx.x;
    if (tid < 10) {
        const float* we = (tid < 5) ? we1 : we2;
        const float* ae = (tid < 5) ? ae1 : ae2;
        int h = tid % 5;
        float s = 0.f;
        for (int c = 0; c < 32; c++) s += we[h * 32 + c] * ae[h * 32 + c];
        s_out[tid] = s;
    }
}

#define ROWFMA(i, s) { acc[i].x += (s)*w4.x; acc[i].y += (s)*w4.y; acc[i].z += (s)*w4.z; acc[i].w += (s)*w4.w; }

// ---- h = A @ W, tile M=64, thread = 16 rows x 4 cols.
// BF: bf16 out + att-dot epilogue. !BF: fp32 out with bias+lrelu (merge MLP).
template <int K, bool BF>
__global__ __launch_bounds__(160) void gemm_kernel(const float* __restrict__ A,
                                                   const float* __restrict__ W,
                                                   const float* __restrict__ a_s,
                                                   const float* __restrict__ a_d,
                                                   const float* __restrict__ bias,
                                                   unsigned short* __restrict__ out_bf,
                                                   float* __restrict__ out_f,
                                                   float* al_s, float* al_d) {
    const int SUBSTRIDE = K * 16 + 4;
    __shared__ float smem[10256];
    int t = threadIdx.x;
    int sub = t / 40, cg = t - sub * 40;
    int base = blockIdx.x * 64;

    for (int idx = t; idx < 64 * K; idx += 160) {
        int r = idx / K, k = idx - r * K;
        int row = base + r;
        float v = (row < NN) ? A[(size_t)row * K + k] : 0.f;
        smem[(r >> 4) * SUBSTRIDE + k * 16 + (r & 15)] = v;
    }
    __syncthreads();

    float4 acc[16];
#pragma unroll
    for (int r = 0; r < 16; r++) acc[r] = make_float4(0.f, 0.f, 0.f, 0.f);

    const float* Wp = W + cg * 4;
    const float* xbase = &smem[sub * SUBSTRIDE];
    for (int k = 0; k < K; k++) {
        float4 w4 = *reinterpret_cast<const float4*>(Wp + (size_t)k * HC);
        const float4* xr = reinterpret_cast<const float4*>(xbase + k * 16);
        float4 q0 = xr[0], q1 = xr[1], q2 = xr[2], q3 = xr[3];
        ROWFMA(0, q0.x) ROWFMA(1, q0.y) ROWFMA(2, q0.z) ROWFMA(3, q0.w)
        ROWFMA(4, q1.x) ROWFMA(5, q1.y) ROWFMA(6, q1.z) ROWFMA(7, q1.w)
        ROWFMA(8, q2.x) ROWFMA(9, q2.y) ROWFMA(10, q2.z) ROWFMA(11, q2.w)
        ROWFMA(12, q3.x) ROWFMA(13, q3.y) ROWFMA(14, q3.z) ROWFMA(15, q3.w)
    }

    if (!BF) {
        float4 b4 = *reinterpret_cast<const float4*>(bias + cg * 4);
#pragma unroll
        for (int r = 0; r < 16; r++) {
            int row = base + sub * 16 + r;
            if (row < NN) {
                float4 o;
                o.x = lrelu(acc[r].x + b4.x, 0.01f);
                o.y = lrelu(acc[r].y + b4.y, 0.01f);
                o.z = lrelu(acc[r].z + b4.z, 0.01f);
                o.w = lrelu(acc[r].w + b4.w, 0.01f);
                *reinterpret_cast<float4*>(&out_f[(size_t)row * HC + cg * 4]) = o;
            }
        }
        return;
    }

#pragma unroll
    for (int r = 0; r < 16; r++) {
        int row = base + sub * 16 + r;
        if (row < NN) {
            uint2 p;
            p.x = (unsigned)f2bf(acc[r].x) | ((unsigned)f2bf(acc[r].y) << 16);
            p.y = (unsigned)f2bf(acc[r].z) | ((unsigned)f2bf(acc[r].w) << 16);
            *reinterpret_cast<uint2*>(&out_bf[(size_t)row * HC + cg * 4]) = p;
        }
    }

    __syncthreads();
    float* hs = smem;
#pragma unroll
    for (int r = 0; r < 16; r++) {
        *reinterpret_cast<float4*>(&hs[(sub * 16 + r) * HC + cg * 4]) = acc[r];
    }
    __syncthreads();
    for (int task = t; task < 640; task += 160) {
        int r = task / 10, rem = task - r * 10;
        int hd = rem >> 1, sd = rem & 1;
        int row = base + r;
        if (row < NN) {
            const float* av = sd ? a_d : a_s;
            float s = 0.f;
#pragma unroll
            for (int c = 0; c < 32; c++) s += hs[r * HC + hd * 32 + c] * av[hd * 32 + c];
            float* dst = sd ? al_d : al_s;
            dst[row * NH + hd] = s;
        }
    }
}

// ------------- one WAVE per node: softmax in registers (lane = item), no barriers
__global__ __launch_bounds__(256) void aggregate_kernel(
    const int* __restrict__ soff, const uint4* __restrict__ erec,
    const unsigned short* __restrict__ hfeat, const float* __restrict__ al_s,
    const float* __restrict__ al_d, const float* __restrict__ s_e,
    const float* __restrict__ bias, const float* __restrict__ g_ln,
    const float* __restrict__ b_ln,
    float* __restrict__ alpha_out, float* __restrict__ x_out) {
    int lane = threadIdx.x & 63, wid = threadIdx.x >> 6;
    int n = blockIdx.x * 4 + wid;
    if (n >= NN) return;
    int s0 = soff[n];
    int deg = soff[n + 1] - s0;
    int items = deg + 1;

    // [wave][head][item] ; 72 stride => head h lands on distinct banks
    __shared__ float wlds[4][NH][72];

    float se[NH], ad[NH];
#pragma unroll
    for (int h = 0; h < NH; h++) { se[h] = s_e[h]; ad[h] = al_d[n * NH + h]; }

    float acc0 = 0.f, acc1 = 0.f, acc2 = 0.f;
    int hsel = lane >> 5;   // 0 or 1

    if (items <= 64) {
        // ---- fast path: lane = item
        int src = n; int opos = EE + n; float ea = 0.f;
        if (lane < deg) {
            uint4 rec = erec[s0 + lane];
            src = (int)rec.x; opos = (int)rec.y; ea = __uint_as_float(rec.z);
        }
        bool act = lane < items;
        // edge-attr mean for the self loop
        float eas = (lane < deg) ? ea : 0.f;
#pragma unroll
        for (int o = 32; o >= 1; o >>= 1) eas += __shfl_xor(eas, o, 64);
        if (lane == deg) ea = eas / fmaxf((float)deg, 1.f);
        // logits
        float r[NH];
#pragma unroll
        for (int h = 0; h < NH; h++)
            r[h] = act ? lrelu(al_s[src * NH + h] + ad[h] + ea * se[h], 0.2f) : -3.0e38f;
        // per-head max + exp + sum (butterflies: every lane holds the result)
        float w[NH];
#pragma unroll
        for (int h = 0; h < NH; h++) {
            float m = r[h];
#pragma unroll
            for (int o = 32; o >= 1; o >>= 1) m = fmaxf(m, __shfl_xor(m, o, 64));
            float e = act ? expf(r[h] - m) : 0.f;
            float s = e;
#pragma unroll
            for (int o = 32; o >= 1; o >>= 1) s += __shfl_xor(s, o, 64);
            w[h] = e / s;
            wlds[wid][h][lane] = w[h];
        }
        if (act) {
#pragma unroll
            for (int h = 0; h < NH; h++) alpha_out[(size_t)opos * NH + h] = w[h];
        }
        // channel-parallel weighted gather: lane owns channels {lane, lane+64, lane+128}
        for (int i = 0; i < items; i++) {
            int sv = __shfl(src, i, 64);
            const unsigned short* hp = hfeat + (size_t)sv * HC;
            float w01 = wlds[wid][hsel][i];
            float w23 = wlds[wid][2 + hsel][i];
            acc0 += w01 * bf2f(hp[lane]);
            acc1 += w23 * bf2f(hp[lane + 64]);
            if (lane < 32) acc2 += wlds[wid][4][i] * bf2f(hp[lane + 128]);
        }
    } else {
        // ---- slow path (deg >= 64, vanishingly rare): online softmax, 2 passes
        float m[NH], ssum[NH];
#pragma unroll
        for (int h = 0; h < NH; h++) { m[h] = -3.0e38f; ssum[h] = 0.f; }
        float eas = 0.f;
        for (int base = 0; base < deg; base += 64) {
            int i = base + lane;
            bool a = i < deg;
            int src = n; float ea = 0.f;
            if (a) { uint4 rec = erec[s0 + i]; src = (int)rec.x; ea = __uint_as_float(rec.z); }
            eas += a ? ea : 0.f;
#pragma unroll
            for (int h = 0; h < NH; h++) {
                float r = a ? lrelu(al_s[src * NH + h] + ad[h] + ea * se[h], 0.2f) : -3.0e38f;
                float cm = r;
#pragma unroll
                for (int o = 32; o >= 1; o >>= 1) cm = fmaxf(cm, __shfl_xor(cm, o, 64));
                float e = a ? expf(r - cm) : 0.f;
                float cs = e;
#pragma unroll
                for (int o = 32; o >= 1; o >>= 1) cs += __shfl_xor(cs, o, 64);
                float nm = fmaxf(m[h], cm);
                ssum[h] = ssum[h] * expf(m[h] - nm) + cs * expf(cm - nm);
                m[h] = nm;
            }
        }
#pragma unroll
        for (int o = 32; o >= 1; o >>= 1) eas += __shfl_xor(eas, o, 64);
        float emean = eas / fmaxf((float)deg, 1.f);
        float rs[NH];
#pragma unroll
        for (int h = 0; h < NH; h++) {
            rs[h] = lrelu(al_s[n * NH + h] + ad[h] + emean * se[h], 0.2f);
            float nm = fmaxf(m[h], rs[h]);
            ssum[h] = ssum[h] * expf(m[h] - nm) + expf(rs[h] - nm);
            m[h] = nm;
        }
        float inv[NH];
#pragma unroll
        for (int h = 0; h < NH; h++) inv[h] = 1.f / ssum[h];
        // pass 2: recompute, normalize, alpha, accumulate
        for (int base = 0; base < deg; base += 64) {
            int i = base + lane;
            bool a = i < deg;
            int src = n; float ea = 0.f; int opos = 0;
            if (a) { uint4 rec = erec[s0 + i]; src = (int)rec.x; opos = (int)rec.y; ea = __uint_as_float(rec.z); }
#pragma unroll
            for (int h = 0; h < NH; h++) {
                float r = a ? lrelu(al_s[src * NH + h] + ad[h] + ea * se[h], 0.2f) : 0.f;
                float w = a ? expf(r - m[h]) * inv[h] : 0.f;
                wlds[wid][h][lane] = w;
                if (a) alpha_out[(size_t)opos * NH + h] = w;
            }
            int clen = min(64, deg - base);
            for (int ii = 0; ii < clen; ii++) {
                int sv = __shfl(src, ii, 64);
                const unsigned short* hp = hfeat + (size_t)sv * HC;
                acc0 += wlds[wid][hsel][ii] * bf2f(hp[lane]);
                acc1 += wlds[wid][2 + hsel][ii] * bf2f(hp[lane + 64]);
                if (lane < 32) acc2 += wlds[wid][4][ii] * bf2f(hp[lane + 128]);
            }
        }
        // self-loop item
        float w0s = expf(rs[0] - m[0]) * inv[0];
        float w1s = expf(rs[1] - m[1]) * inv[1];
        float w2s = expf(rs[2] - m[2]) * inv[2];
        float w3s = expf(rs[3] - m[3]) * inv[3];
        float w4s = expf(rs[4] - m[4]) * inv[4];
        if (lane == 0) {
            float* ap = alpha_out + (size_t)(EE + n) * NH;
            ap[0] = w0s; ap[1] = w1s; ap[2] = w2s; ap[3] = w3s; ap[4] = w4s;
        }
        const unsigned short* hp = hfeat + (size_t)n * HC;
        acc0 += ((lane & 32) ? w1s : w0s) * bf2f(hp[lane]);
        acc1 += ((lane & 32) ? w3s : w2s) * bf2f(hp[lane + 64]);
        if (lane < 32) acc2 += w4s * bf2f(hp[lane + 128]);
    }

    // ---- bias + leaky-relu + LayerNorm over the 160 channels (wave-local)
    float v0 = lrelu(acc0 + bias[lane], 0.01f);
    float v1 = lrelu(acc1 + bias[lane + 64], 0.01f);
    float v2 = (lane < 32) ? lrelu(acc2 + bias[lane + 128], 0.01f) : 0.f;
    float p1 = v0 + v1 + v2;
    float p2 = v0 * v0 + v1 * v1 + v2 * v2;
#pragma unroll
    for (int o = 32; o >= 1; o >>= 1) {
        p1 += __shfl_xor(p1, o, 64);
        p2 += __shfl_xor(p2, o, 64);
    }
    float mean = p1 / (float)HC;
    float var = p2 / (float)HC - mean * mean;
    float rstd = rsqrtf(var + 1e-5f);
    float* xo = x_out + (size_t)n * HC;
    xo[lane]      = (v0 - mean) * rstd * g_ln[lane]       + b_ln[lane];
    xo[lane + 64] = (v1 - mean) * rstd * g_ln[lane + 64]  + b_ln[lane + 64];
    if (lane < 32)
        xo[lane + 128] = (v2 - mean) * rstd * g_ln[lane + 128] + b_ln[lane + 128];
}

// ---- mean-pool stage 1: 16 partitions per graph, one atomicAdd per (block,ch)
__global__ __launch_bounds__(160) void pool1_kernel(const float* __restrict__ x3,
                                                    const int* __restrict__ gstart,
                                                    const int* __restrict__ gcnt,
                                                    float* __restrict__ psum) {
    int g = blockIdx.x / NPART;
    int part = blockIdx.x - g * NPART;
    int c = threadIdx.x;
    int s = gstart[g], cnt = gcnt[g];
    int chunk = (cnt + NPART - 1) / NPART;
    int r0 = part * chunk;
    int r1 = min(cnt, r0 + chunk);
    if (r0 >= r1) return;
    float acc = 0.f;
    for (int r = r0; r < r1; r++) acc += x3[(size_t)(s + r) * HC + c];
    atomicAdd(&psum[g * HC + c], acc);
}

__global__ void pooldiv_kernel(const float* __restrict__ psum, const int* __restrict__ gcnt,
                               float* __restrict__ pooled_out) {
    int i = blockIdx.x * 256 + threadIdx.x;
    if (i < NG * HC) pooled_out[i] = psum[i] / fmaxf((float)gcnt[i / HC], 1.f);
}

// ---------------------------------------------------------------------- launch
extern "C" void kernel_launch(void* const* d_in, const int* in_sizes, int n_in,
                              void* d_out, int out_size, void* d_ws, size_t ws_size,
                              hipStream_t stream) {
    const float* x    = (const float*)d_in[0];
    const int*   ei   = (const int*)d_in[1];
    const float* ea   = (const float*)d_in[2];
    const int*   batch= (const int*)d_in[3];
    const float* w1   = (const float*)d_in[4];
    const float* we1  = (const float*)d_in[5];
    const float* as1  = (const float*)d_in[6];
    const float* ad1  = (const float*)d_in[7];
    const float* ae1  = (const float*)d_in[8];
    const float* b1   = (const float*)d_in[9];
    const float* w2   = (const float*)d_in[10];
    const float* we2  = (const float*)d_in[11];
    const float* as2  = (const float*)d_in[12];
    const float* ad2  = (const float*)d_in[13];
    const float* ae2  = (const float*)d_in[14];
    const float* b2   = (const float*)d_in[15];
    const float* ln1g = (const float*)d_in[16];
    const float* ln1b = (const float*)d_in[17];
    const float* ln2g = (const float*)d_in[18];
    const float* ln2b = (const float*)d_in[19];
    const float* mw   = (const float*)d_in[20];
    const float* mb   = (const float*)d_in[21];

    float* out = (float*)d_out;
    float* x12 = out;
    float* pooled_out = out + (size_t)NN * HC;
    float* a1 = pooled_out + NG * HC;
    float* a2 = a1 + (size_t)(EE + NN) * NH;

    char* wp = (char*)d_ws;
    auto alloc = [&](size_t bytes) {
        void* p = (void*)wp;
        wp += (bytes + 255) & ~(size_t)255;
        return p;
    };
    unsigned short* hbuf16 = (unsigned short*)alloc((size_t)NN * HC * 2);  // 16 MB
    uint4* erec  = (uint4*)alloc((size_t)EE * 16);                          // 12.8 MB
    unsigned short* base_g = hbuf16;            // overlay: dead before gemm1
    unsigned*       hist_g = (unsigned*)erec;   // overlay: dead before scatter
    float* als   = (float*)alloc((size_t)NN * NH * 4);
    float* ald   = (float*)alloc((size_t)NN * NH * 4);
    int*   deg   = (int*)alloc((size_t)NN * 4);
    int*   soff  = (int*)alloc((size_t)(NN + 1) * 4);
    float* sbuf  = (float*)alloc(64);
    float* psum  = (float*)alloc((size_t)NG * HC * 4);
    int*   gcnt  = (int*)alloc((size_t)NG * 4);
    int*   gstart= (int*)alloc((size_t)NG * 4);
    int*   bsum  = (int*)alloc(256 * 4);
    int*   boff  = (int*)alloc(256 * 4);

    prep_kernel<<<40, 256, 0, stream>>>(batch, gstart, gcnt, psum);
    hist_kernel<<<NB, 256, 0, stream>>>(ei, hist_g);
    sscan_kernel<<<49, 256, 0, stream>>>(hist_g, base_g, deg);
    scan1_kernel<<<196, 256, 0, stream>>>(deg, bsum);
    scan2_kernel<<<1, 256, 0, stream>>>(bsum, boff);
    scan3_kernel<<<196, 256, 0, stream>>>(deg, boff, soff);
    scatter_kernel<<<NB, 256, 0, stream>>>(ei, ea, base_g, soff, erec);
    preps_kernel<<<1, 64, 0, stream>>>(we1, ae1, we2, ae2, sbuf);

    gemm_kernel<128, true><<<782, 160, 0, stream>>>(x, w1, as1, ad1, nullptr,
                                                    hbuf16, nullptr, als, ald);
    aggregate_kernel<<<12500, 256, 0, stream>>>(soff, erec, hbuf16, als, ald,
                                                sbuf, b1, ln1g, ln1b, a1, x12);

    gemm_kernel<160, true><<<782, 160, 0, stream>>>(x12, w2, as2, ad2, nullptr,
                                                    hbuf16, nullptr, als, ald);
    aggregate_kernel<<<12500, 256, 0, stream>>>(soff, erec, hbuf16, als, ald,
                                                sbuf + 5, b2, ln2g, ln2b, a2, x12);

    gemm_kernel<160, false><<<782, 160, 0, stream>>>(x12, mw, nullptr, nullptr, mb,
                                                     nullptr, out, nullptr, nullptr);
    pool1_kernel<<<NG * NPART, 160, 0, stream>>>(out, gstart, gcnt, psum);
    pooldiv_kernel<<<40, 256, 0, stream>>>(psum, gcnt, pooled_out);
}